// Round 2
// 1494.036 us; speedup vs baseline: 1.0588x; 1.0588x over previous
//
#include <hip/hip_runtime.h>
#include <hip/hip_bf16.h>

// ---------------------------------------------------------------------------
// GNN pretrain forward: h=relu(x@Wl+bl); 5x [gather-agg -> fusedMLP -> BN]
// R6: fused MLP chunk pipeline, layout FIXED from R5 (AST=136 bug: A tile is
// 64x256, stride must be >=256; rows overlapped -> wrong results).
//   - A tile (64x256 bf16) in LDS at exact stride 256, XOR-swizzled on
//     8-elem groups (g ^= row&7) to kill the 512B-stride bank collision.
//   - hid in 4 chunks of 128 cols, SINGLE buffer (64x136, 17KB); pass1(c+1)
//     compute (global W1T loads + MFMA) still overlaps pass2(c) since it
//     precedes the overwrite barrier.
//   - LDS 50176B -> 3 blocks/CU (was 66KB -> 2), launch_bounds(256,3).
// Theory: fused_mlp was latency-bound (MfmaUtil 11%, VALUBusy 9%, occ 19%);
// more waves/CU + chunk overlap hides L2 weight-load latency.
// ---------------------------------------------------------------------------

typedef __bf16 bf16x8 __attribute__((ext_vector_type(8)));
typedef __bf16 bf16x4 __attribute__((ext_vector_type(4)));
typedef float f32x4 __attribute__((ext_vector_type(4)));

#define LDSTRIDE 40  // gemm0 LDS pad

// ------------------- gemm0 (fp32 in, fp32 out, relu) -----------------------
// 128x128 block tile, 4 waves (2x2), each wave 64x64 = 4x4 MFMA tiles.
__global__ __launch_bounds__(256, 2)
void gemm0_kernel(const float* __restrict__ Av, const __bf16* __restrict__ BT,
                  const float* __restrict__ bias, float* __restrict__ Cv,
                  int M, int K, int Nc)
{
    __shared__ __bf16 As[128 * LDSTRIDE];
    __shared__ __bf16 Bs[128 * LDSTRIDE];

    const int tid  = threadIdx.x;
    const int wave = tid >> 6;
    const int lane = tid & 63;
    const int quad = lane >> 4;
    const int l16  = lane & 15;
    const int wm   = wave >> 1;
    const int wn   = wave & 1;

    const int col0 = blockIdx.x * 128;
    const int row0 = blockIdx.y * 128;

    f32x4 acc[4][4];
#pragma unroll
    for (int mt = 0; mt < 4; ++mt)
#pragma unroll
        for (int nt = 0; nt < 4; ++nt) acc[mt][nt] = (f32x4){0.f, 0.f, 0.f, 0.f};

    const int srow = tid >> 1;
    const int scol = (tid & 1) * 16;
    const int a_row = row0 + srow;
    const bool a_ok = (a_row < M);
    const __bf16* Bp = BT + (size_t)(col0 + srow) * K + scol;

    for (int k0 = 0; k0 < K; k0 += 32) {
        bf16x8 a0, a1;
        const float* Ap = Av + (size_t)a_row * K + k0 + scol;
        f32x4 x0 = {0,0,0,0}, x1 = {0,0,0,0}, x2 = {0,0,0,0}, x3 = {0,0,0,0};
        if (a_ok) {
            x0 = *(const f32x4*)(Ap);
            x1 = *(const f32x4*)(Ap + 4);
            x2 = *(const f32x4*)(Ap + 8);
            x3 = *(const f32x4*)(Ap + 12);
        }
#pragma unroll
        for (int j = 0; j < 4; ++j) {
            a0[j] = (__bf16)x0[j]; a0[4 + j] = (__bf16)x1[j];
            a1[j] = (__bf16)x2[j]; a1[4 + j] = (__bf16)x3[j];
        }
        bf16x8 b0 = *(const bf16x8*)(Bp + k0);
        bf16x8 b1 = *(const bf16x8*)(Bp + k0 + 8);

        __syncthreads();
        *(bf16x8*)&As[srow * LDSTRIDE + scol]     = a0;
        *(bf16x8*)&As[srow * LDSTRIDE + scol + 8] = a1;
        *(bf16x8*)&Bs[srow * LDSTRIDE + scol]     = b0;
        *(bf16x8*)&Bs[srow * LDSTRIDE + scol + 8] = b1;
        __syncthreads();

        bf16x8 af[4], bfr[4];
#pragma unroll
        for (int mt = 0; mt < 4; ++mt)
            af[mt] = *(const bf16x8*)&As[(wm * 64 + mt * 16 + l16) * LDSTRIDE + quad * 8];
#pragma unroll
        for (int nt = 0; nt < 4; ++nt)
            bfr[nt] = *(const bf16x8*)&Bs[(wn * 64 + nt * 16 + l16) * LDSTRIDE + quad * 8];

#pragma unroll
        for (int mt = 0; mt < 4; ++mt)
#pragma unroll
            for (int nt = 0; nt < 4; ++nt)
                acc[mt][nt] = __builtin_amdgcn_mfma_f32_16x16x32_bf16(
                    af[mt], bfr[nt], acc[mt][nt], 0, 0, 0);
    }

#pragma unroll
    for (int nt = 0; nt < 4; ++nt) {
        const int col = col0 + wn * 64 + nt * 16 + l16;
        const float b = bias[col];
#pragma unroll
        for (int mt = 0; mt < 4; ++mt) {
#pragma unroll
            for (int r = 0; r < 4; ++r) {
                const int row = row0 + wm * 64 + mt * 16 + quad * 4 + r;
                if (row < M) {
                    float v = fmaxf(acc[mt][nt][r] + b, 0.f);
                    Cv[(size_t)row * Nc + col] = v;
                }
            }
        }
    }
}

// ------------------- fused MLP: out = relu(A@W1+b1)@W2+b2 + BN stats -------
// M-tile = 64 rows/block, 256 threads (4 waves), 3 blocks/CU.
// A: LDS stride 256 exactly, XOR swizzle (8-elem group ^ (row&7)).
// hid: single 64x136 chunk buffer; 4 chunks of 128 cols; 2 barriers/chunk.
#define HST 136

__global__ __launch_bounds__(256, 3)
void fused_mlp_kernel(const __bf16* __restrict__ aggb,
                      const __bf16* __restrict__ W1T, const float* __restrict__ b1,
                      const __bf16* __restrict__ W2T, const float* __restrict__ b2,
                      float* __restrict__ out, float* __restrict__ sums, int M)
{
    __shared__ __bf16 As[64 * 256];    // 32768 B, swizzled
    __shared__ __bf16 hidS[64 * HST];  // 17408 B

    const int tid  = threadIdx.x;
    const int wave = tid >> 6;
    const int lane = tid & 63;
    const int quad = lane >> 4;
    const int l16  = lane & 15;
    const int row0 = blockIdx.x * 64;

    // ---- stage A tile (64 x 256 bf16) into LDS, swizzled ----
    {
        const int srow = tid >> 2;        // 0..63
        const int gb8  = (tid & 3) * 8;   // first 8-col group (0,8,16,24)
        const int m = row0 + srow;
        bf16x8 v[8];
        if (m < M) {
            const __bf16* Ap = aggb + (size_t)m * 256 + gb8 * 8;
#pragma unroll
            for (int j = 0; j < 8; ++j) v[j] = *(const bf16x8*)(Ap + j * 8);
        } else {
#pragma unroll
            for (int j = 0; j < 8; ++j)
#pragma unroll
                for (int q = 0; q < 8; ++q) v[j][q] = (__bf16)0.f;
        }
#pragma unroll
        for (int j = 0; j < 8; ++j) {
            const int sg = (gb8 + j) ^ (srow & 7);
            *(bf16x8*)&As[srow * 256 + sg * 8] = v[j];
        }
    }
    __syncthreads();

    const int cb = wave * 64;  // pass2 output column base
    f32x4 acc2[4][4];
#pragma unroll
    for (int mt = 0; mt < 4; ++mt)
#pragma unroll
        for (int nt = 0; nt < 4; ++nt) acc2[mt][nt] = (f32x4){0.f, 0.f, 0.f, 0.f};

#pragma unroll 1
    for (int c = 0; c < 4; ++c) {
        // ---- pass 1: hid chunk = relu(A @ W1[:, c*128 .. +128) + b1) ----
        // wave covers 32 cols of the chunk (2 nt tiles).
        const int nbase = c * 128 + wave * 32;
        f32x4 acc1[4][2];
#pragma unroll
        for (int mt = 0; mt < 4; ++mt)
#pragma unroll
            for (int nt = 0; nt < 2; ++nt) acc1[mt][nt] = (f32x4){0.f, 0.f, 0.f, 0.f};

#pragma unroll
        for (int kk = 0; kk < 8; ++kk) {
            bf16x8 Bf[2];
#pragma unroll
            for (int nt = 0; nt < 2; ++nt)
                Bf[nt] = *(const bf16x8*)(W1T + (size_t)(nbase + nt * 16 + l16) * 256
                                          + kk * 32 + quad * 8);
            const int sg = (kk * 4 + quad) ^ (l16 & 7);  // row&7 == l16&7
            bf16x8 af[4];
#pragma unroll
            for (int mt = 0; mt < 4; ++mt)
                af[mt] = *(const bf16x8*)&As[(mt * 16 + l16) * 256 + sg * 8];
#pragma unroll
            for (int mt = 0; mt < 4; ++mt)
#pragma unroll
                for (int nt = 0; nt < 2; ++nt)
                    acc1[mt][nt] = __builtin_amdgcn_mfma_f32_16x16x32_bf16(
                        af[mt], Bf[nt], acc1[mt][nt], 0, 0, 0);
        }

        // wait until everyone is done READING hidS (pass2 of chunk c-1)
        __syncthreads();

        // write chunk (bias + relu, bf16). local col = wave*32 + nt*16 + l16
#pragma unroll
        for (int nt = 0; nt < 2; ++nt) {
            const int lcol = wave * 32 + nt * 16 + l16;
            const float bb = b1[c * 128 + lcol];
#pragma unroll
            for (int mt = 0; mt < 4; ++mt)
#pragma unroll
                for (int r = 0; r < 4; ++r) {
                    float v = fmaxf(acc1[mt][nt][r] + bb, 0.f);
                    hidS[(mt * 16 + quad * 4 + r) * HST + lcol] = (__bf16)v;
                }
        }
        __syncthreads();

        // ---- pass 2: acc2 += hid_chunk @ W2[c*128 .. +128, :] ----
#pragma unroll
        for (int kk = 0; kk < 4; ++kk) {
            bf16x8 Hf[4], Bf2[4];
#pragma unroll
            for (int mt = 0; mt < 4; ++mt)
                Hf[mt] = *(const bf16x8*)&hidS[(mt * 16 + l16) * HST + kk * 32 + quad * 8];
#pragma unroll
            for (int nt = 0; nt < 4; ++nt)
                Bf2[nt] = *(const bf16x8*)(W2T + (size_t)(cb + nt * 16 + l16) * 512
                                           + c * 128 + kk * 32 + quad * 8);
#pragma unroll
            for (int mt = 0; mt < 4; ++mt)
#pragma unroll
                for (int nt = 0; nt < 4; ++nt)
                    acc2[mt][nt] = __builtin_amdgcn_mfma_f32_16x16x32_bf16(
                        Hf[mt], Bf2[nt], acc2[mt][nt], 0, 0, 0);
        }
    }

    // ---- epilogue: bias + store fp32 + fused BN column stats ----
#pragma unroll
    for (int nt = 0; nt < 4; ++nt) {
        const int col = cb + nt * 16 + l16;
        const float bb = b2[col];
        float s = 0.f, ss = 0.f;
#pragma unroll
        for (int mt = 0; mt < 4; ++mt) {
#pragma unroll
            for (int r = 0; r < 4; ++r) {
                const int row = row0 + mt * 16 + quad * 4 + r;
                if (row < M) {
                    float v = acc2[mt][nt][r] + bb;
                    out[(size_t)row * 256 + col] = v;
                    s += v; ss += v * v;
                }
            }
        }
        s += __shfl_xor(s, 16); ss += __shfl_xor(ss, 16);
        s += __shfl_xor(s, 32); ss += __shfl_xor(ss, 32);
        if (lane < 16) {
            atomicAdd(&sums[col], s);
            atomicAdd(&sums[256 + col], ss);
        }
    }
}

// WT[l][n][k] = (bf16) W[l][k][n]
__global__ void convert_wt_kernel(const float* __restrict__ W, __bf16* __restrict__ WT,
                                  int K, int Nc, int total)
{
    int i = blockIdx.x * 256 + threadIdx.x;
    if (i >= total) return;
    int kn = K * Nc;
    int l = i / kn;
    int rem = i - l * kn;
    int n = rem / K;
    int k = rem - n * K;
    WT[i] = (__bf16)W[(size_t)l * kn + (size_t)k * Nc + n];
}

// ------------------------ edge sort (once per launch) ----------------------

__global__ void zero_counts_kernel(int* __restrict__ counts, int N)
{
    int i = blockIdx.x * 256 + threadIdx.x;
    if (i < N) counts[i] = 0;
}

__global__ void hist_kernel(const int* __restrict__ ei, int* __restrict__ counts, int E)
{
    int e = blockIdx.x * 256 + threadIdx.x;
    if (e < E) atomicAdd(&counts[ei[E + e]], 1);
}

__global__ void scan1_kernel(const int* __restrict__ counts, int* __restrict__ partial,
                             int* __restrict__ blocksums, int N)
{
    __shared__ int sm[256];
    int i = blockIdx.x * 256 + threadIdx.x;
    int v = (i < N) ? counts[i] : 0;
    sm[threadIdx.x] = v;
    __syncthreads();
    for (int off = 1; off < 256; off <<= 1) {
        int t = 0;
        if ((int)threadIdx.x >= off) t = sm[threadIdx.x - off];
        __syncthreads();
        if ((int)threadIdx.x >= off) sm[threadIdx.x] += t;
        __syncthreads();
    }
    if (i < N) partial[i] = sm[threadIdx.x] - v;
    if (threadIdx.x == 255) blocksums[blockIdx.x] = sm[255];
}

__global__ void scan2_kernel(int* __restrict__ blocksums, int NB)
{
    __shared__ int sm[1024];
    int v = ((int)threadIdx.x < NB) ? blocksums[threadIdx.x] : 0;
    sm[threadIdx.x] = v;
    __syncthreads();
    for (int off = 1; off < 1024; off <<= 1) {
        int t = 0;
        if ((int)threadIdx.x >= off) t = sm[threadIdx.x - off];
        __syncthreads();
        if ((int)threadIdx.x >= off) sm[threadIdx.x] += t;
        __syncthreads();
    }
    if ((int)threadIdx.x < NB) blocksums[threadIdx.x] = sm[threadIdx.x] - v;
}

__global__ void scan3_kernel(const int* __restrict__ partial, const int* __restrict__ blocksums,
                             int* __restrict__ rowptr, int* __restrict__ woff, int N, int E)
{
    int i = blockIdx.x * 256 + threadIdx.x;
    if (i < N) {
        int v = partial[i] + blocksums[blockIdx.x];
        rowptr[i] = v;
        woff[i] = v;
    }
    if (i == 0) rowptr[N] = E;
}

__global__ void scatter_sort_kernel(const int* __restrict__ ei, const int* __restrict__ ea,
                                    int* __restrict__ woff, int* __restrict__ sorted, int E)
{
    int e = blockIdx.x * 256 + threadIdx.x;
    if (e >= E) return;
    int dst = ei[E + e];
    int src = ei[e];
    int c = ea[2 * e] * 3 + ea[2 * e + 1];
    int pos = atomicAdd(&woff[dst], 1);
    sorted[pos] = (src << 4) | c;
}

// ------------------------ per-layer kernels --------------------------------

__global__ void build_table_kernel(const float* __restrict__ E1, const float* __restrict__ E2,
                                   int l, float* __restrict__ tab, float* __restrict__ selfemb,
                                   float* __restrict__ sums)
{
    int b = blockIdx.x;
    int t = threadIdx.x;
    const float* e1 = E1 + (size_t)l * 6 * 256;
    const float* e2 = E2 + (size_t)l * 3 * 256;
    if (b < 9) {
        tab[b * 256 + t] = e1[(b / 3) * 256 + t] + e2[(b % 3) * 256 + t];
    } else {
        selfemb[t] = e1[4 * 256 + t] + e2[0 * 256 + t];
        sums[t] = 0.f;
        sums[256 + t] = 0.f;
    }
}

// aggb[n] = bf16( bn(out[n]) + selfemb + sum_e (bn(out[src_e]) + tab[c_e]) )
// tab/selfemb read straight from global (10KB, L1-resident). No LDS.
template<int APPLY_BN>
__global__ __launch_bounds__(256)
void gather_kernel(const float* __restrict__ out, const int* __restrict__ rowptr,
                   const int* __restrict__ sorted, const float* __restrict__ tab,
                   const float* __restrict__ selfemb, const float* __restrict__ scsh,
                   __bf16* __restrict__ aggb, int N)
{
    int n = blockIdx.x * 4 + (threadIdx.x >> 6);
    if (n >= N) return;
    int lane = threadIdx.x & 63;
    int f = lane * 4;

    f32x4 sc, sh;
    if (APPLY_BN) {
        sc = *(const f32x4*)(scsh + f);
        sh = *(const f32x4*)(scsh + 256 + f);
    }

    int r0 = rowptr[n];
    int r1 = rowptr[n + 1];

    f32x4 hv = *(const f32x4*)(out + (size_t)n * 256 + f);
    if (APPLY_BN) hv = hv * sc + sh;
    f32x4 acc = hv + *(const f32x4*)(selfemb + f);

    for (int e = r0; e < r1; ++e) {
        int v = sorted[e];
        f32x4 xv = *(const f32x4*)(out + (size_t)(v >> 4) * 256 + f);
        if (APPLY_BN) xv = xv * sc + sh;
        acc += xv + *(const f32x4*)(tab + (v & 15) * 256 + f);
    }
    bf16x4 o;
#pragma unroll
    for (int j = 0; j < 4; ++j) o[j] = (__bf16)acc[j];
    *(bf16x4*)(aggb + (size_t)n * 256 + f) = o;
}

__global__ void bn_finalize_kernel(const float* __restrict__ sums,
                                   const float* __restrict__ gamma,
                                   const float* __restrict__ beta,
                                   int l, int M, float* __restrict__ scsh)
{
    int c = threadIdx.x;  // 256
    float inv = 1.f / (float)M;
    float mean = sums[c] * inv;
    float var = sums[256 + c] * inv - mean * mean;
    float sc = gamma[l * 256 + c] * rsqrtf(var + 1e-5f);
    scsh[c] = sc;
    scsh[256 + c] = beta[l * 256 + c] - mean * sc;
}

// h = out * scale + shift  (final layer only)
__global__ __launch_bounds__(256)
void bn_apply_kernel(const float* __restrict__ out, const float* __restrict__ scsh,
                     float* __restrict__ h, int total4)
{
    int i = blockIdx.x * 256 + threadIdx.x;
    if (i >= total4) return;
    int cg = i & 63;
    f32x4 sc = ((const f32x4*)scsh)[cg];
    f32x4 sh = ((const f32x4*)scsh)[64 + cg];
    f32x4 v = ((const f32x4*)out)[i];
    ((f32x4*)h)[i] = v * sc + sh;
}

extern "C" void kernel_launch(void* const* d_in, const int* in_sizes, int n_in,
                              void* d_out, int out_size, void* d_ws, size_t ws_size,
                              hipStream_t stream)
{
    const float* x     = (const float*)d_in[0];
    const int*   ei    = (const int*)d_in[1];
    const int*   ea    = (const int*)d_in[2];
    const float* Wl    = (const float*)d_in[3];
    const float* bl    = (const float*)d_in[4];
    const float* W1    = (const float*)d_in[5];
    const float* b1    = (const float*)d_in[6];
    const float* W2    = (const float*)d_in[7];
    const float* b2    = (const float*)d_in[8];
    const float* E1    = (const float*)d_in[9];
    const float* E2    = (const float*)d_in[10];
    const float* gamma = (const float*)d_in[11];
    const float* beta  = (const float*)d_in[12];

    const int N = in_sizes[0] / 128;
    const int E = in_sizes[1] / 2;

    // d_out space doubles as the bf16 agg buffer; final bn_apply overwrites it.
    __bf16* aggb = (__bf16*)d_out;               // N x 256 bf16
    float*  hfin = (float*)d_out;                // final output view

    // workspace layout
    float*  out  = (float*)d_ws;                     // N x 256 fp32
    __bf16* WlT  = (__bf16*)(out + (size_t)N * 256); // 256 x 128
    __bf16* W1T  = WlT + 256 * 128;                  // 5 x 512 x 256
    __bf16* W2T  = W1T + 5 * 512 * 256;              // 5 x 256 x 512
    float*  tab  = (float*)(W2T + 5 * 256 * 512);    // 9 x 256
    float*  selfemb = tab + 9 * 256;                 // 256
    float*  sums = selfemb + 256;                    // 512
    float*  scsh = sums + 512;                       // 512
    int*    counts = (int*)(scsh + 512);             // N
    int*    partial = counts + N;                    // N
    int*    rowptr  = partial + N;                   // N+1
    int*    woff    = rowptr + N + 1;                // N
    int*    sorted  = woff + N;                      // E
    int*    blocksums = sorted + E;                  // <=1024

    const int NB = (N + 255) / 256;
    const int EB = (E + 255) / 256;

    // --- edge sort by dst (edges constant across layers) ---
    zero_counts_kernel<<<NB, 256, 0, stream>>>(counts, N);
    hist_kernel<<<EB, 256, 0, stream>>>(ei, counts, E);
    scan1_kernel<<<NB, 256, 0, stream>>>(counts, partial, blocksums, N);
    scan2_kernel<<<1, 1024, 0, stream>>>(blocksums, NB);
    scan3_kernel<<<NB, 256, 0, stream>>>(partial, blocksums, rowptr, woff, N, E);
    scatter_sort_kernel<<<EB, 256, 0, stream>>>(ei, ea, woff, sorted, E);

    // --- weight conversion (transposed bf16) ---
    convert_wt_kernel<<<(128 * 256 + 255) / 256, 256, 0, stream>>>(Wl, WlT, 128, 256, 128 * 256);
    convert_wt_kernel<<<(5 * 256 * 512 + 255) / 256, 256, 0, stream>>>(W1, W1T, 256, 512, 5 * 256 * 512);
    convert_wt_kernel<<<(5 * 512 * 256 + 255) / 256, 256, 0, stream>>>(W2, W2T, 512, 256, 5 * 512 * 256);

    const int mtiles128 = (N + 127) / 128;
    const int mtiles64  = (N + 63) / 64;
    const int total4 = N * 64;
    const int ew_blocks = (total4 + 255) / 256;
    const int gb = (N + 3) / 4;

    // out = relu(x @ Wl + bl)
    gemm0_kernel<<<dim3(2, mtiles128), 256, 0, stream>>>(x, WlT, bl, out, N, 128, 256);

    for (int l = 0; l < 5; ++l) {
        build_table_kernel<<<10, 256, 0, stream>>>(E1, E2, l, tab, selfemb, sums);
        if (l == 0)
            gather_kernel<0><<<gb, 256, 0, stream>>>(out, rowptr, sorted, tab, selfemb,
                                                     scsh, aggb, N);
        else
            gather_kernel<1><<<gb, 256, 0, stream>>>(out, rowptr, sorted, tab, selfemb,
                                                     scsh, aggb, N);
        fused_mlp_kernel<<<mtiles64, 256, 0, stream>>>(
            aggb, W1T + (size_t)l * 512 * 256, b1 + l * 512,
            W2T + (size_t)l * 256 * 512, b2 + l * 256, out, sums, N);
        bn_finalize_kernel<<<1, 256, 0, stream>>>(sums, gamma, beta, l, N, scsh);
    }
    // final h = bn(out) -> d_out (fp32)
    bn_apply_kernel<<<ew_blocks, 256, 0, stream>>>(out, scsh, hfin, total4);
}

// Round 3
// 1460.858 us; speedup vs baseline: 1.0828x; 1.0227x over previous
//
#include <hip/hip_runtime.h>
#include <hip/hip_bf16.h>

// ---------------------------------------------------------------------------
// GNN pretrain forward: h=relu(x@Wl+bl); 5x [gather-agg -> fusedMLP -> BN]
// R7: fused MLP as a phase-overlapped pipeline.
//   - 8 chunks of 64 hid cols; hid double-buffered (2 x 64x72 bf16, 18KB);
//     ONE barrier per iteration.
//   - Per iter: issue W1-loads(c) + W2-loads(c-1) at top, then pass2(c-1)
//     MFMAs (hide W1 latency), then pass1(c) MFMAs, then hid write.
//   - Atomic BN sums 8-way replicated by blockIdx&7 (per-address chain
//     1563 -> 195), folded in bn_finalize.
// Theory: R6 was ~85% stall with no saturated pipe -> structural phase
// serialization (every phase ate full L2 latency) + same-address atomic tail.
// ---------------------------------------------------------------------------

typedef __bf16 bf16x8 __attribute__((ext_vector_type(8)));
typedef __bf16 bf16x4 __attribute__((ext_vector_type(4)));
typedef float f32x4 __attribute__((ext_vector_type(4)));

#define LDSTRIDE 40  // gemm0 LDS pad

// ------------------- gemm0 (fp32 in, fp32 out, relu) -----------------------
// 128x128 block tile, 4 waves (2x2), each wave 64x64 = 4x4 MFMA tiles.
__global__ __launch_bounds__(256, 2)
void gemm0_kernel(const float* __restrict__ Av, const __bf16* __restrict__ BT,
                  const float* __restrict__ bias, float* __restrict__ Cv,
                  int M, int K, int Nc)
{
    __shared__ __bf16 As[128 * LDSTRIDE];
    __shared__ __bf16 Bs[128 * LDSTRIDE];

    const int tid  = threadIdx.x;
    const int wave = tid >> 6;
    const int lane = tid & 63;
    const int quad = lane >> 4;
    const int l16  = lane & 15;
    const int wm   = wave >> 1;
    const int wn   = wave & 1;

    const int col0 = blockIdx.x * 128;
    const int row0 = blockIdx.y * 128;

    f32x4 acc[4][4];
#pragma unroll
    for (int mt = 0; mt < 4; ++mt)
#pragma unroll
        for (int nt = 0; nt < 4; ++nt) acc[mt][nt] = (f32x4){0.f, 0.f, 0.f, 0.f};

    const int srow = tid >> 1;
    const int scol = (tid & 1) * 16;
    const int a_row = row0 + srow;
    const bool a_ok = (a_row < M);
    const __bf16* Bp = BT + (size_t)(col0 + srow) * K + scol;

    for (int k0 = 0; k0 < K; k0 += 32) {
        bf16x8 a0, a1;
        const float* Ap = Av + (size_t)a_row * K + k0 + scol;
        f32x4 x0 = {0,0,0,0}, x1 = {0,0,0,0}, x2 = {0,0,0,0}, x3 = {0,0,0,0};
        if (a_ok) {
            x0 = *(const f32x4*)(Ap);
            x1 = *(const f32x4*)(Ap + 4);
            x2 = *(const f32x4*)(Ap + 8);
            x3 = *(const f32x4*)(Ap + 12);
        }
#pragma unroll
        for (int j = 0; j < 4; ++j) {
            a0[j] = (__bf16)x0[j]; a0[4 + j] = (__bf16)x1[j];
            a1[j] = (__bf16)x2[j]; a1[4 + j] = (__bf16)x3[j];
        }
        bf16x8 b0 = *(const bf16x8*)(Bp + k0);
        bf16x8 b1 = *(const bf16x8*)(Bp + k0 + 8);

        __syncthreads();
        *(bf16x8*)&As[srow * LDSTRIDE + scol]     = a0;
        *(bf16x8*)&As[srow * LDSTRIDE + scol + 8] = a1;
        *(bf16x8*)&Bs[srow * LDSTRIDE + scol]     = b0;
        *(bf16x8*)&Bs[srow * LDSTRIDE + scol + 8] = b1;
        __syncthreads();

        bf16x8 af[4], bfr[4];
#pragma unroll
        for (int mt = 0; mt < 4; ++mt)
            af[mt] = *(const bf16x8*)&As[(wm * 64 + mt * 16 + l16) * LDSTRIDE + quad * 8];
#pragma unroll
        for (int nt = 0; nt < 4; ++nt)
            bfr[nt] = *(const bf16x8*)&Bs[(wn * 64 + nt * 16 + l16) * LDSTRIDE + quad * 8];

#pragma unroll
        for (int mt = 0; mt < 4; ++mt)
#pragma unroll
            for (int nt = 0; nt < 4; ++nt)
                acc[mt][nt] = __builtin_amdgcn_mfma_f32_16x16x32_bf16(
                    af[mt], bfr[nt], acc[mt][nt], 0, 0, 0);
    }

#pragma unroll
    for (int nt = 0; nt < 4; ++nt) {
        const int col = col0 + wn * 64 + nt * 16 + l16;
        const float b = bias[col];
#pragma unroll
        for (int mt = 0; mt < 4; ++mt) {
#pragma unroll
            for (int r = 0; r < 4; ++r) {
                const int row = row0 + wm * 64 + mt * 16 + quad * 4 + r;
                if (row < M) {
                    float v = fmaxf(acc[mt][nt][r] + b, 0.f);
                    Cv[(size_t)row * Nc + col] = v;
                }
            }
        }
    }
}

// ------------------- fused MLP: out = relu(A@W1+b1)@W2+b2 + BN stats -------
// M-tile = 64 rows/block, 256 threads (4 waves), 3 blocks/CU.
// A: LDS stride 256, XOR swizzle (8-elem group ^ (row&7)).
// hid: 8 chunks of 64 cols, double-buffered 64x72; 1 barrier/iter pipeline.
#define HST 72

__global__ __launch_bounds__(256, 3)
void fused_mlp_kernel(const __bf16* __restrict__ aggb,
                      const __bf16* __restrict__ W1T, const float* __restrict__ b1,
                      const __bf16* __restrict__ W2T, const float* __restrict__ b2,
                      float* __restrict__ out, float* __restrict__ sums, int M)
{
    __shared__ __bf16 As[64 * 256];        // 32768 B, swizzled
    __shared__ __bf16 hidS[2][64 * HST];   // 18432 B (double buffer)

    const int tid  = threadIdx.x;
    const int wave = tid >> 6;
    const int lane = tid & 63;
    const int quad = lane >> 4;
    const int l16  = lane & 15;
    const int row0 = blockIdx.x * 64;

    // ---- stage A tile (64 x 256 bf16) into LDS, swizzled ----
    {
        const int srow = tid >> 2;        // 0..63
        const int gb8  = (tid & 3) * 8;   // first 8-col group (0,8,16,24)
        const int m = row0 + srow;
        bf16x8 v[8];
        if (m < M) {
            const __bf16* Ap = aggb + (size_t)m * 256 + gb8 * 8;
#pragma unroll
            for (int j = 0; j < 8; ++j) v[j] = *(const bf16x8*)(Ap + j * 8);
        } else {
#pragma unroll
            for (int j = 0; j < 8; ++j)
#pragma unroll
                for (int q = 0; q < 8; ++q) v[j][q] = (__bf16)0.f;
        }
#pragma unroll
        for (int j = 0; j < 8; ++j) {
            const int sg = (gb8 + j) ^ (srow & 7);
            *(bf16x8*)&As[srow * 256 + sg * 8] = v[j];
        }
    }

    const int cb = wave * 64;  // pass2 output column base
    f32x4 acc2[4][4];
#pragma unroll
    for (int mt = 0; mt < 4; ++mt)
#pragma unroll
        for (int nt = 0; nt < 4; ++nt) acc2[mt][nt] = (f32x4){0.f, 0.f, 0.f, 0.f};

    // W1T row for this wave's pass1 cols (16 cols per wave per chunk)
    const __bf16* W1p = W1T + (size_t)(wave * 16 + l16) * 256 + quad * 8;
    const __bf16* W2p = W2T + (size_t)(cb + l16) * 512 + quad * 8;

#pragma unroll 1
    for (int c = 0; c <= 8; ++c) {
        __syncthreads();

        // ---- issue W1 loads for chunk c (consumed at end of this iter) ----
        bf16x8 W1f[8];
        if (c < 8) {
            const __bf16* p = W1p + (size_t)(c * 64) * 256;
#pragma unroll
            for (int kk = 0; kk < 8; ++kk)
                W1f[kk] = *(const bf16x8*)(p + kk * 32);
        }

        // ---- pass2(c-1): acc2 += hid(c-1) @ W2[(c-1)*64 .. +64, :] ----
        if (c >= 1) {
            bf16x8 W2f[4][2];
#pragma unroll
            for (int nt = 0; nt < 4; ++nt)
#pragma unroll
                for (int kkl = 0; kkl < 2; ++kkl)
                    W2f[nt][kkl] = *(const bf16x8*)(W2p + (size_t)(nt * 16) * 512
                                                    + (c - 1) * 64 + kkl * 32);
            const __bf16* buf = hidS[(c - 1) & 1];
#pragma unroll
            for (int kkl = 0; kkl < 2; ++kkl) {
                bf16x8 Hf[4];
#pragma unroll
                for (int mt = 0; mt < 4; ++mt)
                    Hf[mt] = *(const bf16x8*)&buf[(mt * 16 + l16) * HST + kkl * 32 + quad * 8];
#pragma unroll
                for (int mt = 0; mt < 4; ++mt)
#pragma unroll
                    for (int nt = 0; nt < 4; ++nt)
                        acc2[mt][nt] = __builtin_amdgcn_mfma_f32_16x16x32_bf16(
                            Hf[mt], W2f[nt][kkl], acc2[mt][nt], 0, 0, 0);
            }
        }

        // ---- pass1(c): hid chunk = relu(A @ W1[:, c*64 .. +64) + b1) ----
        if (c < 8) {
            f32x4 acc1[4];
#pragma unroll
            for (int mt = 0; mt < 4; ++mt) acc1[mt] = (f32x4){0.f, 0.f, 0.f, 0.f};
#pragma unroll
            for (int kk = 0; kk < 8; ++kk) {
                const int sg = (kk * 4 + quad) ^ (l16 & 7);
                bf16x8 af[4];
#pragma unroll
                for (int mt = 0; mt < 4; ++mt)
                    af[mt] = *(const bf16x8*)&As[(mt * 16 + l16) * 256 + sg * 8];
#pragma unroll
                for (int mt = 0; mt < 4; ++mt)
                    acc1[mt] = __builtin_amdgcn_mfma_f32_16x16x32_bf16(
                        af[mt], W1f[kk], acc1[mt], 0, 0, 0);
            }
            // write chunk c (bias + relu, bf16) to buf[c&1]
            __bf16* buf = hidS[c & 1];
            const int lcol = wave * 16 + l16;
            const float bb = b1[c * 64 + lcol];
#pragma unroll
            for (int mt = 0; mt < 4; ++mt)
#pragma unroll
                for (int r = 0; r < 4; ++r) {
                    float v = fmaxf(acc1[mt][r] + bb, 0.f);
                    buf[(mt * 16 + quad * 4 + r) * HST + lcol] = (__bf16)v;
                }
        }
    }

    // ---- epilogue: bias + store fp32 + BN stats (8-way replicated) ----
    float* srep = sums + (blockIdx.x & 7) * 512;
#pragma unroll
    for (int nt = 0; nt < 4; ++nt) {
        const int col = cb + nt * 16 + l16;
        const float bb = b2[col];
        float s = 0.f, ss = 0.f;
#pragma unroll
        for (int mt = 0; mt < 4; ++mt) {
#pragma unroll
            for (int r = 0; r < 4; ++r) {
                const int row = row0 + mt * 16 + quad * 4 + r;
                if (row < M) {
                    float v = acc2[mt][nt][r] + bb;
                    out[(size_t)row * 256 + col] = v;
                    s += v; ss += v * v;
                }
            }
        }
        s += __shfl_xor(s, 16); ss += __shfl_xor(ss, 16);
        s += __shfl_xor(s, 32); ss += __shfl_xor(ss, 32);
        if (lane < 16) {
            atomicAdd(&srep[col], s);
            atomicAdd(&srep[256 + col], ss);
        }
    }
}

// WT[l][n][k] = (bf16) W[l][k][n]
__global__ void convert_wt_kernel(const float* __restrict__ W, __bf16* __restrict__ WT,
                                  int K, int Nc, int total)
{
    int i = blockIdx.x * 256 + threadIdx.x;
    if (i >= total) return;
    int kn = K * Nc;
    int l = i / kn;
    int rem = i - l * kn;
    int n = rem / K;
    int k = rem - n * K;
    WT[i] = (__bf16)W[(size_t)l * kn + (size_t)k * Nc + n];
}

// ------------------------ edge sort (once per launch) ----------------------

__global__ void zero_counts_kernel(int* __restrict__ counts, int N)
{
    int i = blockIdx.x * 256 + threadIdx.x;
    if (i < N) counts[i] = 0;
}

__global__ void hist_kernel(const int* __restrict__ ei, int* __restrict__ counts, int E)
{
    int e = blockIdx.x * 256 + threadIdx.x;
    if (e < E) atomicAdd(&counts[ei[E + e]], 1);
}

__global__ void scan1_kernel(const int* __restrict__ counts, int* __restrict__ partial,
                             int* __restrict__ blocksums, int N)
{
    __shared__ int sm[256];
    int i = blockIdx.x * 256 + threadIdx.x;
    int v = (i < N) ? counts[i] : 0;
    sm[threadIdx.x] = v;
    __syncthreads();
    for (int off = 1; off < 256; off <<= 1) {
        int t = 0;
        if ((int)threadIdx.x >= off) t = sm[threadIdx.x - off];
        __syncthreads();
        if ((int)threadIdx.x >= off) sm[threadIdx.x] += t;
        __syncthreads();
    }
    if (i < N) partial[i] = sm[threadIdx.x] - v;
    if (threadIdx.x == 255) blocksums[blockIdx.x] = sm[255];
}

__global__ void scan2_kernel(int* __restrict__ blocksums, int NB)
{
    __shared__ int sm[1024];
    int v = ((int)threadIdx.x < NB) ? blocksums[threadIdx.x] : 0;
    sm[threadIdx.x] = v;
    __syncthreads();
    for (int off = 1; off < 1024; off <<= 1) {
        int t = 0;
        if ((int)threadIdx.x >= off) t = sm[threadIdx.x - off];
        __syncthreads();
        if ((int)threadIdx.x >= off) sm[threadIdx.x] += t;
        __syncthreads();
    }
    if ((int)threadIdx.x < NB) blocksums[threadIdx.x] = sm[threadIdx.x] - v;
}

__global__ void scan3_kernel(const int* __restrict__ partial, const int* __restrict__ blocksums,
                             int* __restrict__ rowptr, int* __restrict__ woff, int N, int E)
{
    int i = blockIdx.x * 256 + threadIdx.x;
    if (i < N) {
        int v = partial[i] + blocksums[blockIdx.x];
        rowptr[i] = v;
        woff[i] = v;
    }
    if (i == 0) rowptr[N] = E;
}

__global__ void scatter_sort_kernel(const int* __restrict__ ei, const int* __restrict__ ea,
                                    int* __restrict__ woff, int* __restrict__ sorted, int E)
{
    int e = blockIdx.x * 256 + threadIdx.x;
    if (e >= E) return;
    int dst = ei[E + e];
    int src = ei[e];
    int c = ea[2 * e] * 3 + ea[2 * e + 1];
    int pos = atomicAdd(&woff[dst], 1);
    sorted[pos] = (src << 4) | c;
}

// ------------------------ per-layer kernels --------------------------------

__global__ void build_table_kernel(const float* __restrict__ E1, const float* __restrict__ E2,
                                   int l, float* __restrict__ tab, float* __restrict__ selfemb,
                                   float* __restrict__ sums)
{
    int b = blockIdx.x;
    int t = threadIdx.x;
    const float* e1 = E1 + (size_t)l * 6 * 256;
    const float* e2 = E2 + (size_t)l * 3 * 256;
    if (b < 9) {
        tab[b * 256 + t] = e1[(b / 3) * 256 + t] + e2[(b % 3) * 256 + t];
    } else {
        selfemb[t] = e1[4 * 256 + t] + e2[0 * 256 + t];
#pragma unroll
        for (int r = 0; r < 16; ++r) sums[r * 256 + t] = 0.f;  // 8 replicas x 512
    }
}

// aggb[n] = bf16( bn(out[n]) + selfemb + sum_e (bn(out[src_e]) + tab[c_e]) )
// tab/selfemb read straight from global (10KB, L1-resident). No LDS.
template<int APPLY_BN>
__global__ __launch_bounds__(256)
void gather_kernel(const float* __restrict__ out, const int* __restrict__ rowptr,
                   const int* __restrict__ sorted, const float* __restrict__ tab,
                   const float* __restrict__ selfemb, const float* __restrict__ scsh,
                   __bf16* __restrict__ aggb, int N)
{
    int n = blockIdx.x * 4 + (threadIdx.x >> 6);
    if (n >= N) return;
    int lane = threadIdx.x & 63;
    int f = lane * 4;

    f32x4 sc, sh;
    if (APPLY_BN) {
        sc = *(const f32x4*)(scsh + f);
        sh = *(const f32x4*)(scsh + 256 + f);
    }

    int r0 = rowptr[n];
    int r1 = rowptr[n + 1];

    f32x4 hv = *(const f32x4*)(out + (size_t)n * 256 + f);
    if (APPLY_BN) hv = hv * sc + sh;
    f32x4 acc = hv + *(const f32x4*)(selfemb + f);

    for (int e = r0; e < r1; ++e) {
        int v = sorted[e];
        f32x4 xv = *(const f32x4*)(out + (size_t)(v >> 4) * 256 + f);
        if (APPLY_BN) xv = xv * sc + sh;
        acc += xv + *(const f32x4*)(tab + (v & 15) * 256 + f);
    }
    bf16x4 o;
#pragma unroll
    for (int j = 0; j < 4; ++j) o[j] = (__bf16)acc[j];
    *(bf16x4*)(aggb + (size_t)n * 256 + f) = o;
}

__global__ void bn_finalize_kernel(const float* __restrict__ sums,
                                   const float* __restrict__ gamma,
                                   const float* __restrict__ beta,
                                   int l, int M, float* __restrict__ scsh)
{
    int c = threadIdx.x;  // 256
    float s = 0.f, ss = 0.f;
#pragma unroll
    for (int r = 0; r < 8; ++r) {
        s  += sums[r * 512 + c];
        ss += sums[r * 512 + 256 + c];
    }
    float inv = 1.f / (float)M;
    float mean = s * inv;
    float var = ss * inv - mean * mean;
    float sc = gamma[l * 256 + c] * rsqrtf(var + 1e-5f);
    scsh[c] = sc;
    scsh[256 + c] = beta[l * 256 + c] - mean * sc;
}

// h = out * scale + shift  (final layer only)
__global__ __launch_bounds__(256)
void bn_apply_kernel(const float* __restrict__ out, const float* __restrict__ scsh,
                     float* __restrict__ h, int total4)
{
    int i = blockIdx.x * 256 + threadIdx.x;
    if (i >= total4) return;
    int cg = i & 63;
    f32x4 sc = ((const f32x4*)scsh)[cg];
    f32x4 sh = ((const f32x4*)scsh)[64 + cg];
    f32x4 v = ((const f32x4*)out)[i];
    ((f32x4*)h)[i] = v * sc + sh;
}

extern "C" void kernel_launch(void* const* d_in, const int* in_sizes, int n_in,
                              void* d_out, int out_size, void* d_ws, size_t ws_size,
                              hipStream_t stream)
{
    const float* x     = (const float*)d_in[0];
    const int*   ei    = (const int*)d_in[1];
    const int*   ea    = (const int*)d_in[2];
    const float* Wl    = (const float*)d_in[3];
    const float* bl    = (const float*)d_in[4];
    const float* W1    = (const float*)d_in[5];
    const float* b1    = (const float*)d_in[6];
    const float* W2    = (const float*)d_in[7];
    const float* b2    = (const float*)d_in[8];
    const float* E1    = (const float*)d_in[9];
    const float* E2    = (const float*)d_in[10];
    const float* gamma = (const float*)d_in[11];
    const float* beta  = (const float*)d_in[12];

    const int N = in_sizes[0] / 128;
    const int E = in_sizes[1] / 2;

    // d_out space doubles as the bf16 agg buffer; final bn_apply overwrites it.
    __bf16* aggb = (__bf16*)d_out;               // N x 256 bf16
    float*  hfin = (float*)d_out;                // final output view

    // workspace layout
    float*  out  = (float*)d_ws;                     // N x 256 fp32
    __bf16* WlT  = (__bf16*)(out + (size_t)N * 256); // 256 x 128
    __bf16* W1T  = WlT + 256 * 128;                  // 5 x 512 x 256
    __bf16* W2T  = W1T + 5 * 512 * 256;              // 5 x 256 x 512
    float*  tab  = (float*)(W2T + 5 * 256 * 512);    // 9 x 256
    float*  selfemb = tab + 9 * 256;                 // 256
    float*  sums = selfemb + 256;                    // 8 replicas x 512 = 4096
    float*  scsh = sums + 4096;                      // 512
    int*    counts = (int*)(scsh + 512);             // N
    int*    partial = counts + N;                    // N
    int*    rowptr  = partial + N;                   // N+1
    int*    woff    = rowptr + N + 1;                // N
    int*    sorted  = woff + N;                      // E
    int*    blocksums = sorted + E;                  // <=1024

    const int NB = (N + 255) / 256;
    const int EB = (E + 255) / 256;

    // --- edge sort by dst (edges constant across layers) ---
    zero_counts_kernel<<<NB, 256, 0, stream>>>(counts, N);
    hist_kernel<<<EB, 256, 0, stream>>>(ei, counts, E);
    scan1_kernel<<<NB, 256, 0, stream>>>(counts, partial, blocksums, N);
    scan2_kernel<<<1, 1024, 0, stream>>>(blocksums, NB);
    scan3_kernel<<<NB, 256, 0, stream>>>(partial, blocksums, rowptr, woff, N, E);
    scatter_sort_kernel<<<EB, 256, 0, stream>>>(ei, ea, woff, sorted, E);

    // --- weight conversion (transposed bf16) ---
    convert_wt_kernel<<<(128 * 256 + 255) / 256, 256, 0, stream>>>(Wl, WlT, 128, 256, 128 * 256);
    convert_wt_kernel<<<(5 * 256 * 512 + 255) / 256, 256, 0, stream>>>(W1, W1T, 256, 512, 5 * 256 * 512);
    convert_wt_kernel<<<(5 * 512 * 256 + 255) / 256, 256, 0, stream>>>(W2, W2T, 512, 256, 5 * 512 * 256);

    const int mtiles128 = (N + 127) / 128;
    const int mtiles64  = (N + 63) / 64;
    const int total4 = N * 64;
    const int ew_blocks = (total4 + 255) / 256;
    const int gb = (N + 3) / 4;

    // out = relu(x @ Wl + bl)
    gemm0_kernel<<<dim3(2, mtiles128), 256, 0, stream>>>(x, WlT, bl, out, N, 128, 256);

    for (int l = 0; l < 5; ++l) {
        build_table_kernel<<<10, 256, 0, stream>>>(E1, E2, l, tab, selfemb, sums);
        if (l == 0)
            gather_kernel<0><<<gb, 256, 0, stream>>>(out, rowptr, sorted, tab, selfemb,
                                                     scsh, aggb, N);
        else
            gather_kernel<1><<<gb, 256, 0, stream>>>(out, rowptr, sorted, tab, selfemb,
                                                     scsh, aggb, N);
        fused_mlp_kernel<<<mtiles64, 256, 0, stream>>>(
            aggb, W1T + (size_t)l * 512 * 256, b1 + l * 512,
            W2T + (size_t)l * 256 * 512, b2 + l * 256, out, sums, N);
        bn_finalize_kernel<<<1, 256, 0, stream>>>(sums, gamma, beta, l, N, scsh);
    }
    // final h = bn(out) -> d_out (fp32)
    bn_apply_kernel<<<ew_blocks, 256, 0, stream>>>(out, scsh, hfin, total4);
}